// Round 12
// baseline (4116.239 us; speedup 1.0000x reference)
//
#include <hip/hip_runtime.h>
#include <hip/hip_bf16.h>

// LSTM B=1024 T=256 IN=64 H=512. Round 17 (byte-identical resubmit of R16
// after an infra 'container failed twice'; R7/R8 precedent: identical
// resubmission ran fine). Design recap:
// Dual-chain + tagged prefetch. R15 proved the tagged exchange (8B units
// {2xf16, u32 step-tag}, fire-and-forget stores, no drain/no flags) is
// correct but still WAITS synchronously for h at each step start. R14
// proved dual-chain phases alone don't help when each phase embeds its
// serial exchange. Combination: per iteration, phase A{tag-check prefetched
// regs -> stage -> sync -> ISSUE chain-B loads -> MFMA -> epilogue} then
// phase B{... -> ISSUE chain-A loads for t+1 ...}. The h-load rtt flies
// under the other phase's MFMA+epilogue; the check normally passes
// instantly; stale tags (store/load race) -> rare reload.
// Chains: A = rows [p*16,+16), B = rows [512+p*16,+16), same jb => SAME
// weights (bfr shared, R14-proven). 16-row A-tiles waste the upper half of
// the 32x32 MFMA (C regs 8..15 garbage, epilogue reads 0..7) -> MFMA issue
// 2x (~+0.12us/step-equiv) -- accepted.
// Safety: 3-slot rotation argument unchanged; tag equality (memset 0 each
// launch) certifies freshness; LDS reuse ordered by the other phase's
// barrier; watchdog on the retry loop -> wrong answer, never a hang.

#define TST   256
#define BATCH 1024
#define HID   512
#define INSZ  64
#define NCLS  10
#define LDSTR 584   // elem stride: 1168 B = 292 dw = 4 mod 32 -> conflict-free

typedef _Float16 f16x8  __attribute__((ext_vector_type(8)));
typedef float    f32x16 __attribute__((ext_vector_type(16)));
typedef unsigned long long u64;

__device__ __forceinline__ float fast_rcp(float x) {
    return __builtin_amdgcn_rcpf(x);   // v_rcp_f32, ~1 ulp
}
__device__ __forceinline__ float tanh_f(float x) {
    return 2.0f * fast_rcp(1.0f + __expf(-2.0f * x)) - 1.0f;
}
__device__ __forceinline__ f16x8 cvt8(float4 a, float4 b) {
    f16x8 o;
    o[0] = (_Float16)a.x; o[1] = (_Float16)a.y; o[2] = (_Float16)a.z; o[3] = (_Float16)a.w;
    o[4] = (_Float16)b.x; o[5] = (_Float16)b.y; o[6] = (_Float16)b.z; o[7] = (_Float16)b.w;
    return o;
}
__device__ __forceinline__ u64 cvt4_u64(float4 a) {
    _Float16 h[4] = {(_Float16)a.x, (_Float16)a.y, (_Float16)a.z, (_Float16)a.w};
    u64 r; __builtin_memcpy(&r, h, 8); return r;
}
template <int CTRL>
__device__ __forceinline__ float dpp_f(float v) {
    return __builtin_bit_cast(float,
        __builtin_amdgcn_mov_dpp(__builtin_bit_cast(int, v), CTRL, 0xF, 0xF, true));
}
template <int CTRL>
__device__ __forceinline__ unsigned dpp_u(unsigned v) {
    return (unsigned)__builtin_amdgcn_mov_dpp((int)v, CTRL, 0xF, 0xF, true);
}
// DPP ctrls: quad_perm xor1=0xB1, xor2=0x4E, xor3=0x1B; row_shl:4=0x104.

__global__ __launch_bounds__(256, 1) void lstm_persist(
    const float* __restrict__ x,   const float* __restrict__ h0,
    const float* __restrict__ c0,  const float* __restrict__ Wih,
    const float* __restrict__ Whh, const float* __restrict__ bih,
    const float* __restrict__ bhh, u64* __restrict__ hb)
{
    // Two 32-row tiles; rows 0..15 staged per chain, 16..31 garbage (their
    // MFMA products land in C regs 8..15, never read).
    __shared__ __align__(16) _Float16 As[2][32][LDSTR];   // 74752 B

    const int tid   = threadIdx.x;
    const int lane  = tid & 63;
    const int w     = tid >> 6;        // wave 0..3
    const int l31   = lane & 31;
    const int khalf = (lane >> 5) * 8;
    const int p  = (int)(blockIdx.x >> 3);   // group-pair 0..31
    const int jb = (int)(blockIdx.x & 7);    // j-block 0..7
    const int j0 = jb * 64;
    const int mbA = p * 16;            // chain A batch rows
    const int mbB = 512 + p * 16;      // chain B batch rows

    const int gate = l31 & 3;          // nt*32 preserves np&3
    int jcol[2], nrow[2];
    #pragma unroll
    for (int nt = 0; nt < 2; ++nt) {
        int np = w * 64 + nt * 32 + l31;
        jcol[nt] = j0 + (np >> 2);
        nrow[nt] = gate * HID + jcol[nt];
    }

    // ---- B fragments in registers (one-time, SHARED by both chains) ----
    f16x8 bfr[2][36];
    #pragma unroll
    for (int nt = 0; nt < 2; ++nt)
        #pragma unroll
        for (int kt = 0; kt < 36; ++kt) {
            const int k0 = kt * 16 + khalf;
            const float* ptr = (kt < 32) ? (Whh + (size_t)nrow[nt] * HID + k0)
                                         : (Wih + (size_t)nrow[nt] * INSZ + (k0 - HID));
            float4 f0 = ((const float4*)ptr)[0];
            float4 f1 = ((const float4*)ptr)[1];
            bfr[nt][kt] = cvt8(f0, f1);
        }
    float bsv[2];
    bsv[0] = bih[nrow[0]] + bhh[nrow[0]];
    bsv[1] = bih[nrow[1]] + bhh[nrow[1]];
    const float s   = (gate == 2) ? 2.0f : 1.0f;   // tanh for g, sigmoid otherwise
    const int rowhi = (lane >> 5) * 4;

    // ---- c state: [chain][nt][r 0..7] -> rows 0..15 ----
    float cr[2][2][8];
    #pragma unroll
    for (int ch = 0; ch < 2; ++ch)
        #pragma unroll
        for (int nt = 0; nt < 2; ++nt)
            #pragma unroll
            for (int r = 0; r < 8; ++r) {
                int row = (r & 3) + 8 * (r >> 2) + rowhi;   // 0..15
                int mb  = ch ? mbB : mbA;
                cr[ch][nt][r] = c0[(size_t)(mb + row) * HID + jcol[nt]];
            }

    const int rr = tid >> 4;       // staging: 16 threads per row (16 rows)
    const int q  = tid & 15;

    u64 hvA[16], hvB[16];          // prefetched tagged h (one row-slice each)

    for (int t = 0; t < TST; ++t) {
        const u64* rb = hb + (size_t)((t + 2) % 3) * (BATCH * HID / 2);
        u64*       wb = hb + (size_t)(t % 3) * (BATCH * HID / 2);
        const u64 tag64 = ((u64)(unsigned)(t + 1)) << 32;
        const unsigned tgt = (unsigned)t;

        // ================= phase A (chain A, step t) =================
        {
            float4 xv = *(const float4*)(x + (size_t)(mbA + rr) * (TST * INSZ)
                                           + t * INSZ + q * 4);
            if (t == 0) {
                #pragma unroll
                for (int u = 0; u < 8; ++u) {
                    float4 f = *(const float4*)(h0 + (size_t)(mbA + rr) * HID
                                                  + q * 4 + u * 64);
                    *(u64*)&As[0][rr][q * 4 + u * 64] = cvt4_u64(f);
                }
            } else {
                // hvA prefetched during phase B(t-1): check tags, rare retry
                const u64* rbq = rb + (size_t)(mbA + rr) * 256;
                int spins = 0;
                while (true) {
                    unsigned bad = 0;
                    #pragma unroll
                    for (int u = 0; u < 16; ++u)
                        bad |= ((unsigned)(hvA[u] >> 32)) ^ tgt;
                    if (__all((int)(bad == 0))) break;
                    if (++spins > (1 << 14)) break;   // watchdog
                    __builtin_amdgcn_s_sleep(8);
                    #pragma unroll
                    for (int u = 0; u < 16; ++u)
                        hvA[u] = __hip_atomic_load(&rbq[q + u * 16],
                                                   __ATOMIC_RELAXED,
                                                   __HIP_MEMORY_SCOPE_AGENT);
                }
                __atomic_signal_fence(__ATOMIC_SEQ_CST);
                #pragma unroll
                for (int u = 0; u < 16; ++u)
                    *(unsigned*)&As[0][rr][(q + u * 16) * 2] = (unsigned)hvA[u];
            }
            *(u64*)&As[0][rr][512 + q * 4] = cvt4_u64(xv);
            __syncthreads();

            // issue chain-B loads (h_B(t-1), stored a full phase ago)
            if (t >= 1) {
                const u64* rbq = rb + (size_t)(mbB + rr) * 256;
                #pragma unroll
                for (int u = 0; u < 16; ++u)
                    hvB[u] = __hip_atomic_load(&rbq[q + u * 16],
                                               __ATOMIC_RELAXED,
                                               __HIP_MEMORY_SCOPE_AGENT);
                __atomic_signal_fence(__ATOMIC_SEQ_CST);
            }

            f32x16 acc[2];
            #pragma unroll
            for (int i = 0; i < 16; ++i) { acc[0][i] = 0.0f; acc[1][i] = 0.0f; }
            #pragma unroll
            for (int kt = 0; kt < 36; ++kt) {
                f16x8 af = *(const f16x8*)&As[0][l31][kt * 16 + khalf];
                acc[0] = __builtin_amdgcn_mfma_f32_32x32x16_f16(af, bfr[0][kt], acc[0], 0, 0, 0);
                acc[1] = __builtin_amdgcn_mfma_f32_32x32x16_f16(af, bfr[1][kt], acc[1], 0, 0, 0);
            }

            #pragma unroll
            for (int nt = 0; nt < 2; ++nt)
                #pragma unroll
                for (int r = 0; r < 8; ++r) {
                    float v = acc[nt][r] + bsv[nt];
                    float e = __expf(-s * v);
                    float act = s * fast_rcp(1.0f + e) - (s - 1.0f);
                    float fu = dpp_f<0xB1>(act);
                    float gu = dpp_f<0x4E>(act);
                    float ou = dpp_f<0x1B>(act);
                    float cn = fu * cr[0][nt][r] + act * gu;
                    cr[0][nt][r] = cn;
                    float hn = ou * tanh_f(cn);
                    unsigned hu = (unsigned)__builtin_bit_cast(unsigned short, (_Float16)hn);
                    unsigned pk = hu | (dpp_u<0x104>(hu) << 16);
                    if ((l31 & 7) == 0) {
                        int row = (r & 3) + 8 * (r >> 2) + rowhi;   // 0..15
                        __hip_atomic_store(
                            wb + ((size_t)(mbA + row) * HID + jcol[nt]) / 2,
                            (u64)pk | tag64,
                            __ATOMIC_RELAXED, __HIP_MEMORY_SCOPE_AGENT);
                    }
                }
        }

        // ================= phase B (chain B, step t) =================
        {
            float4 xv = *(const float4*)(x + (size_t)(mbB + rr) * (TST * INSZ)
                                           + t * INSZ + q * 4);
            if (t == 0) {
                #pragma unroll
                for (int u = 0; u < 8; ++u) {
                    float4 f = *(const float4*)(h0 + (size_t)(mbB + rr) * HID
                                                  + q * 4 + u * 64);
                    *(u64*)&As[1][rr][q * 4 + u * 64] = cvt4_u64(f);
                }
            } else {
                const u64* rbq = rb + (size_t)(mbB + rr) * 256;
                int spins = 0;
                while (true) {
                    unsigned bad = 0;
                    #pragma unroll
                    for (int u = 0; u < 16; ++u)
                        bad |= ((unsigned)(hvB[u] >> 32)) ^ tgt;
                    if (__all((int)(bad == 0))) break;
                    if (++spins > (1 << 14)) break;   // watchdog
                    __builtin_amdgcn_s_sleep(8);
                    #pragma unroll
                    for (int u = 0; u < 16; ++u)
                        hvB[u] = __hip_atomic_load(&rbq[q + u * 16],
                                                   __ATOMIC_RELAXED,
                                                   __HIP_MEMORY_SCOPE_AGENT);
                }
                __atomic_signal_fence(__ATOMIC_SEQ_CST);
                #pragma unroll
                for (int u = 0; u < 16; ++u)
                    *(unsigned*)&As[1][rr][(q + u * 16) * 2] = (unsigned)hvB[u];
            }
            *(u64*)&As[1][rr][512 + q * 4] = cvt4_u64(xv);
            __syncthreads();

            // issue chain-A loads for step t+1 (h_A(t), stored in phase A above;
            // remote skew may race -> caught by A's tag check, rare retry)
            if (t < TST - 1) {
                const u64* nbq = hb + (size_t)(t % 3) * (BATCH * HID / 2)
                                    + (size_t)(mbA + rr) * 256;
                #pragma unroll
                for (int u = 0; u < 16; ++u)
                    hvA[u] = __hip_atomic_load(&nbq[q + u * 16],
                                               __ATOMIC_RELAXED,
                                               __HIP_MEMORY_SCOPE_AGENT);
                __atomic_signal_fence(__ATOMIC_SEQ_CST);
            }

            f32x16 acc[2];
            #pragma unroll
            for (int i = 0; i < 16; ++i) { acc[0][i] = 0.0f; acc[1][i] = 0.0f; }
            #pragma unroll
            for (int kt = 0; kt < 36; ++kt) {
                f16x8 af = *(const f16x8*)&As[1][l31][kt * 16 + khalf];
                acc[0] = __builtin_amdgcn_mfma_f32_32x32x16_f16(af, bfr[0][kt], acc[0], 0, 0, 0);
                acc[1] = __builtin_amdgcn_mfma_f32_32x32x16_f16(af, bfr[1][kt], acc[1], 0, 0, 0);
            }

            #pragma unroll
            for (int nt = 0; nt < 2; ++nt)
                #pragma unroll
                for (int r = 0; r < 8; ++r) {
                    float v = acc[nt][r] + bsv[nt];
                    float e = __expf(-s * v);
                    float act = s * fast_rcp(1.0f + e) - (s - 1.0f);
                    float fu = dpp_f<0xB1>(act);
                    float gu = dpp_f<0x4E>(act);
                    float ou = dpp_f<0x1B>(act);
                    float cn = fu * cr[1][nt][r] + act * gu;
                    cr[1][nt][r] = cn;
                    float hn = ou * tanh_f(cn);
                    unsigned hu = (unsigned)__builtin_bit_cast(unsigned short, (_Float16)hn);
                    unsigned pk = hu | (dpp_u<0x104>(hu) << 16);
                    if ((l31 & 7) == 0) {
                        int row = (r & 3) + 8 * (r >> 2) + rowhi;   // 0..15
                        __hip_atomic_store(
                            wb + ((size_t)(mbB + row) * HID + jcol[nt]) / 2,
                            (u64)pk | tag64,
                            __ATOMIC_RELAXED, __HIP_MEMORY_SCOPE_AGENT);
                    }
                }
        }
        // no release section: tags are the release.
    }
}

// ---------------- final linear: preds = hT @ W_lin^T + b_lin ----------------
__global__ __launch_bounds__(256) void final_kernel(
    const u64* __restrict__ h, const float* __restrict__ Wl,
    const float* __restrict__ bl, float* __restrict__ out)
{
    int i = blockIdx.x * 256 + threadIdx.x;
    if (i >= BATCH * NCLS) return;
    int b = i / NCLS, c = i - b * NCLS;
    const u64* hp = h + (size_t)b * (HID / 2);
    const float2* wp = (const float2*)(Wl + (size_t)c * HID);
    float sacc = bl[c];
    #pragma unroll 8
    for (int k2 = 0; k2 < HID / 2; ++k2) {
        unsigned lo = (unsigned)hp[k2];
        _Float16 h0v = __builtin_bit_cast(_Float16, (unsigned short)(lo & 0xFFFF));
        _Float16 h1v = __builtin_bit_cast(_Float16, (unsigned short)(lo >> 16));
        float2 wv = wp[k2];
        sacc += (float)h0v * wv.x + (float)h1v * wv.y;
    }
    out[i] = sacc;
}

extern "C" void kernel_launch(void* const* d_in, const int* in_sizes, int n_in,
                              void* d_out, int out_size, void* d_ws, size_t ws_size,
                              hipStream_t stream)
{
    const float* x    = (const float*)d_in[0];
    const float* h0   = (const float*)d_in[1];
    const float* c0   = (const float*)d_in[2];
    const float* Wih  = (const float*)d_in[3];
    const float* Whh  = (const float*)d_in[4];
    const float* bih  = (const float*)d_in[5];
    const float* bhh  = (const float*)d_in[6];
    const float* Wlin = (const float*)d_in[7];
    const float* blin = (const float*)d_in[8];
    float* out = (float*)d_out;

    u64* hb = (u64*)d_ws;   // 3 slots x 2MB tagged h buffers

    // zero all tags each launch (fresh run -> tag 0 < expected everywhere)
    hipMemsetAsync(d_ws, 0, 3 * (size_t)(BATCH * HID / 2) * 8, stream);

    // 256 blocks, 1/CU: each block pipelines two independent 16-row chains
    // (rows p*16 and 512+p*16, same jb => shared weights).
    lstm_persist<<<256, 256, 0, stream>>>(x, h0, c0, Wih, Whh, bih, bhh, hb);

    // step t=255 wrote slot (255 % 3) == 0 -> hb
    final_kernel<<<(BATCH * NCLS + 255) / 256, 256, 0, stream>>>(hb, Wlin, blin, out);
}

// Round 13
// 2294.437 us; speedup vs baseline: 1.7940x; 1.7940x over previous
//
#include <hip/hip_runtime.h>
#include <hip/hip_bf16.h>

// LSTM B=1024 T=256 IN=64 H=512. Round 18: chunk-granular arrival pipeline
// on the tagged exchange. R15 (wait-ALL 32 tags, then stage-all, then
// MFMA-all) paid a wait on the SLOWEST of 8 producers + full rtt serially.
// R16's early prefetch failed (inter-block skew ~ prefetch lead -> retry
// storm). This round issues all 32 tagged loads at step start (no early
// prefetch) and consumes them in 8 chunk-phases:
//   phase j: check chunk j's 4 tags (compiler-counted vmcnt: only waits
//            for those 4 loads) -> stage chunk j -> lgkmcnt(0) + RAW
//            s_barrier (vmcnt NOT drained; later chunks stay in flight)
//            -> MFMA k-tiles 4j..4j+3 (chunk 7: + x tiles 32..35).
// Chunk 0 exposes one rtt; chunks 1..7 arrive under preceding phases, and
// producer j gets j*(phase) extra slack (staggered straggler absorption).
// __syncthreads (drains vmcnt(0) -> would serialize) is replaced by raw
// s_barrier; the end-of-step LDS race is removed by DOUBLE-BUFFERING As
// (t&1): laggard waves MFMA As[t&1] while early waves stage As[(t+1)&1].
// Exactly 8 uniform barriers/step -> no divergent-barrier hang; watchdog
// on every retry loop -> wrong answer, never a wedged container.
// Epilogue unchanged from R15: fire-and-forget tagged 8B stores {2xf16,
// u32 step-tag}, no drain, no flags; 3-slot rotation; tags memset 0 each
// launch. Weights register-resident; DPP gate combine; fast rcp.

#define TST   256
#define BATCH 1024
#define HID   512
#define INSZ  64
#define NCLS  10
#define LDSTR 584   // elem stride: 1168 B = 292 dw = 4 mod 32 -> conflict-free

typedef _Float16 f16x8  __attribute__((ext_vector_type(8)));
typedef float    f32x16 __attribute__((ext_vector_type(16)));
typedef unsigned long long u64;

__device__ __forceinline__ float fast_rcp(float x) {
    return __builtin_amdgcn_rcpf(x);   // v_rcp_f32, ~1 ulp
}
__device__ __forceinline__ float tanh_f(float x) {
    return 2.0f * fast_rcp(1.0f + __expf(-2.0f * x)) - 1.0f;
}
__device__ __forceinline__ f16x8 cvt8(float4 a, float4 b) {
    f16x8 o;
    o[0] = (_Float16)a.x; o[1] = (_Float16)a.y; o[2] = (_Float16)a.z; o[3] = (_Float16)a.w;
    o[4] = (_Float16)b.x; o[5] = (_Float16)b.y; o[6] = (_Float16)b.z; o[7] = (_Float16)b.w;
    return o;
}
__device__ __forceinline__ u64 cvt4_u64(float4 a) {
    _Float16 h[4] = {(_Float16)a.x, (_Float16)a.y, (_Float16)a.z, (_Float16)a.w};
    u64 r; __builtin_memcpy(&r, h, 8); return r;
}
template <int CTRL>
__device__ __forceinline__ float dpp_f(float v) {
    return __builtin_bit_cast(float,
        __builtin_amdgcn_mov_dpp(__builtin_bit_cast(int, v), CTRL, 0xF, 0xF, true));
}
template <int CTRL>
__device__ __forceinline__ unsigned dpp_u(unsigned v) {
    return (unsigned)__builtin_amdgcn_mov_dpp((int)v, CTRL, 0xF, 0xF, true);
}
// DPP ctrls: quad_perm xor1=0xB1, xor2=0x4E, xor3=0x1B; row_shl:4=0x104.

// raw workgroup barrier: LDS ops drained, vmcnt (in-flight global loads)
// deliberately NOT drained. "memory" clobbers fence the compiler both ways.
__device__ __forceinline__ void phase_barrier() {
    asm volatile("s_waitcnt lgkmcnt(0)" ::: "memory");
    __builtin_amdgcn_s_barrier();
    asm volatile("" ::: "memory");
}

__global__ __launch_bounds__(256, 1) void lstm_persist(
    const float* __restrict__ x,   const float* __restrict__ h0,
    const float* __restrict__ c0,  const float* __restrict__ Wih,
    const float* __restrict__ Whh, const float* __restrict__ bih,
    const float* __restrict__ bhh, u64* __restrict__ hb)
{
    __shared__ __align__(16) _Float16 As[2][32][LDSTR];   // 74752 B, dbuf

    const int tid   = threadIdx.x;
    const int lane  = tid & 63;
    const int w     = tid >> 6;        // wave 0..3
    const int l31   = lane & 31;
    const int khalf = (lane >> 5) * 8;
    const int g  = (int)(blockIdx.x >> 3);   // m-group 0..31
    const int jb = (int)(blockIdx.x & 7);    // j-block 0..7
    const int m0 = g * 32;
    const int j0 = jb * 64;

    const int gate = l31 & 3;                // nt*32 preserves np&3
    int jcol[2], nrow[2];
    #pragma unroll
    for (int nt = 0; nt < 2; ++nt) {
        int np = w * 64 + nt * 32 + l31;
        jcol[nt] = j0 + (np >> 2);
        nrow[nt] = gate * HID + jcol[nt];
    }

    // ---- B fragments in registers (one-time): bfr[nt][kt] ----
    f16x8 bfr[2][36];
    #pragma unroll
    for (int nt = 0; nt < 2; ++nt)
        #pragma unroll
        for (int kt = 0; kt < 36; ++kt) {
            const int k0 = kt * 16 + khalf;
            const float* p = (kt < 32) ? (Whh + (size_t)nrow[nt] * HID + k0)
                                       : (Wih + (size_t)nrow[nt] * INSZ + (k0 - HID));
            float4 f0 = ((const float4*)p)[0];
            float4 f1 = ((const float4*)p)[1];
            bfr[nt][kt] = cvt8(f0, f1);
        }
    float bsv[2];
    bsv[0] = bih[nrow[0]] + bhh[nrow[0]];
    bsv[1] = bih[nrow[1]] + bhh[nrow[1]];
    const float s   = (gate == 2) ? 2.0f : 1.0f;   // tanh for g, sigmoid otherwise
    const int rowhi = (lane >> 5) * 4;

    // ---- c state in registers ----
    float cr[2][16];
    #pragma unroll
    for (int nt = 0; nt < 2; ++nt)
        #pragma unroll
        for (int r = 0; r < 16; ++r) {
            int row = (r & 3) + 8 * (r >> 2) + rowhi;
            cr[nt][r] = c0[(size_t)(m0 + row) * HID + jcol[nt]];
        }

    const int rr = tid >> 3;       // staging: 8 threads per row (32 rows)
    const int q  = tid & 7;

    for (int t = 0; t < TST; ++t) {
        const u64* rb = hb + (size_t)((t + 2) % 3) * (BATCH * HID / 2);
        u64*       wb = hb + (size_t)(t % 3) * (BATCH * HID / 2);
        const unsigned tgt = (unsigned)t;
        const u64 tag64 = ((u64)(unsigned)(t + 1)) << 32;
        const int buf = t & 1;
        const u64* rbq = rb + (size_t)(m0 + rr) * 256;

        // ---- issue ALL h loads up front (t>0); consumed chunk-by-chunk ----
        u64 hv[32];
        if (t > 0) {
            #pragma unroll
            for (int u = 0; u < 32; ++u)
                hv[u] = __hip_atomic_load(&rbq[q + u * 8],
                                          __ATOMIC_RELAXED, __HIP_MEMORY_SCOPE_AGENT);
        }

        // ---- x staging (independent of tags) ----
        {
            const float* xp = x + (size_t)(m0 + rr) * (TST * INSZ) + t * INSZ + q * 8;
            float4 x0 = ((const float4*)xp)[0];
            float4 x1 = ((const float4*)xp)[1];
            *(f16x8*)&As[buf][rr][512 + q * 8] = cvt8(x0, x1);
        }
        if (t == 0) {
            // stage h0 fully (no tags); barriers below stay uniform
            #pragma unroll
            for (int u = 0; u < 16; ++u) {
                float4 f = *(const float4*)(h0 + (size_t)(m0 + rr) * HID + q * 4 + u * 32);
                *(u64*)&As[buf][rr][q * 4 + u * 32] = cvt4_u64(f);
            }
        }

        // ---- 8 chunk-phases: check -> stage -> barrier -> MFMA ----
        f32x16 acc[2];
        #pragma unroll
        for (int i = 0; i < 16; ++i) { acc[0][i] = 0.0f; acc[1][i] = 0.0f; }

        #pragma unroll
        for (int j = 0; j < 8; ++j) {
            if (t > 0) {
                // tag check for chunk j (4 loads; compiler emits a counted
                // vmcnt wait for exactly these). Retry rare; watchdog 2^14.
                int spins = 0;
                while (true) {
                    unsigned bad = 0;
                    #pragma unroll
                    for (int u = 0; u < 4; ++u)
                        bad |= ((unsigned)(hv[j * 4 + u] >> 32)) ^ tgt;
                    if (__all((int)(bad == 0))) break;
                    if (++spins > (1 << 14)) break;   // watchdog
                    __builtin_amdgcn_s_sleep(8);
                    #pragma unroll
                    for (int u = 0; u < 4; ++u)
                        hv[j * 4 + u] = __hip_atomic_load(&rbq[q + (j * 4 + u) * 8],
                                                          __ATOMIC_RELAXED,
                                                          __HIP_MEMORY_SCOPE_AGENT);
                }
                __atomic_signal_fence(__ATOMIC_SEQ_CST);
                #pragma unroll
                for (int u = 0; u < 4; ++u)
                    *(unsigned*)&As[buf][rr][(q + (j * 4 + u) * 8) * 2] =
                        (unsigned)hv[j * 4 + u];
            }
            phase_barrier();   // LDS visible; later-chunk loads stay in flight

            const int ktEnd = (j == 7) ? 36 : (j * 4 + 4);
            for (int kt = j * 4; kt < ktEnd; ++kt) {
                f16x8 af = *(const f16x8*)&As[buf][l31][kt * 16 + khalf];
                acc[0] = __builtin_amdgcn_mfma_f32_32x32x16_f16(af, bfr[0][kt], acc[0], 0, 0, 0);
                acc[1] = __builtin_amdgcn_mfma_f32_32x32x16_f16(af, bfr[1][kt], acc[1], 0, 0, 0);
            }
        }

        // ---- epilogue: DPP gate combine, c/h update, tagged 8B stores
        // (fire-and-forget: the tag IS the release; no drain, no flags) ----
        #pragma unroll
        for (int nt = 0; nt < 2; ++nt) {
            #pragma unroll
            for (int r = 0; r < 16; ++r) {
                float v = acc[nt][r] + bsv[nt];
                float e = __expf(-s * v);
                float act = s * fast_rcp(1.0f + e) - (s - 1.0f);   // sigmoid or tanh
                float fu = dpp_f<0xB1>(act);   // quad xor1: f
                float gu = dpp_f<0x4E>(act);   // quad xor2: g
                float ou = dpp_f<0x1B>(act);   // quad xor3: o
                float cn = fu * cr[nt][r] + act * gu;
                cr[nt][r] = cn;
                float hn = ou * tanh_f(cn);
                unsigned hu = (unsigned)__builtin_bit_cast(unsigned short, (_Float16)hn);
                unsigned pk = hu | (dpp_u<0x104>(hu) << 16);   // {h(c), h(c+1)}
                if ((l31 & 7) == 0) {
                    int row = (r & 3) + 8 * (r >> 2) + rowhi;
                    __hip_atomic_store(
                        wb + ((size_t)(m0 + row) * HID + jcol[nt]) / 2,
                        (u64)pk | tag64,
                        __ATOMIC_RELAXED, __HIP_MEMORY_SCOPE_AGENT);
                }
            }
        }
        // no release section, no trailing barrier: As double-buffer makes
        // next-step staging safe while laggard waves finish this step.
    }
}

// ---------------- final linear: preds = hT @ W_lin^T + b_lin ----------------
__global__ __launch_bounds__(256) void final_kernel(
    const u64* __restrict__ h, const float* __restrict__ Wl,
    const float* __restrict__ bl, float* __restrict__ out)
{
    int i = blockIdx.x * 256 + threadIdx.x;
    if (i >= BATCH * NCLS) return;
    int b = i / NCLS, c = i - b * NCLS;
    const u64* hp = h + (size_t)b * (HID / 2);
    const float2* wp = (const float2*)(Wl + (size_t)c * HID);
    float sacc = bl[c];
    #pragma unroll 8
    for (int k2 = 0; k2 < HID / 2; ++k2) {
        unsigned lo = (unsigned)hp[k2];
        _Float16 h0v = __builtin_bit_cast(_Float16, (unsigned short)(lo & 0xFFFF));
        _Float16 h1v = __builtin_bit_cast(_Float16, (unsigned short)(lo >> 16));
        float2 wv = wp[k2];
        sacc += (float)h0v * wv.x + (float)h1v * wv.y;
    }
    out[i] = sacc;
}

extern "C" void kernel_launch(void* const* d_in, const int* in_sizes, int n_in,
                              void* d_out, int out_size, void* d_ws, size_t ws_size,
                              hipStream_t stream)
{
    const float* x    = (const float*)d_in[0];
    const float* h0   = (const float*)d_in[1];
    const float* c0   = (const float*)d_in[2];
    const float* Wih  = (const float*)d_in[3];
    const float* Whh  = (const float*)d_in[4];
    const float* bih  = (const float*)d_in[5];
    const float* bhh  = (const float*)d_in[6];
    const float* Wlin = (const float*)d_in[7];
    const float* blin = (const float*)d_in[8];
    float* out = (float*)d_out;

    u64* hb = (u64*)d_ws;   // 3 slots x 2MB tagged h buffers

    // zero all tags each launch (fresh run -> tag 0 < expected everywhere)
    hipMemsetAsync(d_ws, 0, 3 * (size_t)(BATCH * HID / 2) * 8, stream);

    // 256 blocks, 1/CU (launch_bounds(256,1), 74.8KB LDS) -> all co-resident.
    lstm_persist<<<256, 256, 0, stream>>>(x, h0, c0, Wih, Whh, bih, bhh, hb);

    // step t=255 wrote slot (255 % 3) == 0 -> hb
    final_kernel<<<(BATCH * NCLS + 255) / 256, 256, 0, stream>>>(hb, Wlin, blin, out);
}